// Round 9
// baseline (429.559 us; speedup 1.0000x reference)
//
#include <hip/hip_runtime.h>
#include <math.h>

#define L_NUM 4
#define K_CB  2048
#define D_DIM 256
#define N_ROWS 32768
#define CAP 56            // per-row candidate slots (LDS)
#define WACC  0.12f       // collect window (>= 2x worst-case fp16 dot err ~0.032)
#define WACC2 0.125f      // filter window (collect + packing quantization margin)

typedef _Float16 half8 __attribute__((ext_vector_type(8)));
typedef _Float16 half4v __attribute__((ext_vector_type(4)));
typedef float f32x16 __attribute__((ext_vector_type(16)));

__device__ __forceinline__ void gl_lds16(const void* g, void* l) {
  __builtin_amdgcn_global_load_lds(
      (const __attribute__((address_space(1))) void*)g,
      (__attribute__((address_space(3))) void*)l, 16, 0, 0);
}
// monotone float<->uint encoding for atomicMax on floats
__device__ __forceinline__ unsigned fenc(float f) {
  unsigned u = __float_as_uint(f);
  return (u & 0x80000000u) ? ~u : (u | 0x80000000u);
}
__device__ __forceinline__ float fdec(unsigned k) {
  unsigned u = (k & 0x80000000u) ? (k ^ 0x80000000u) : ~k;
  return __uint_as_float(u);
}

// ---------- prep: den (max(norm,eps)) + cb16 image, K-slot-major chunks ----------
// image chunk c (32 per layer) = cols [(c>>3)*512 .. +512), K-halves [(c&7)*32 .. +32)
// within chunk: [4 subslots][512 cols][8 halves]
__global__ __launch_bounds__(64)
void prep_all_kernel(const float* __restrict__ cb,
                     float* __restrict__ den_out,
                     _Float16* __restrict__ cb16) {
  const int b = blockIdx.x;            // l*2048 + k
  const int k = b & 2047, l = b >> 11;
  const int lane = threadIdx.x;        // 4 dims each
  float4 v = reinterpret_cast<const float4*>(cb + (size_t)b * D_DIM)[lane];
  float s = v.x*v.x + v.y*v.y + v.z*v.z + v.w*v.w;
  #pragma unroll
  for (int m = 1; m < 64; m <<= 1) s += __shfl_xor(s, m, 64);
  const float den = fmaxf(sqrtf(s), 1e-12f);
  if (lane == 0) den_out[b] = den;
  v.x /= den; v.y /= den; v.z /= den; v.w /= den;   // true division = reference rounding
  half4v h;
  h[0] = (_Float16)v.x; h[1] = (_Float16)v.y; h[2] = (_Float16)v.z; h[3] = (_Float16)v.w;
  const int tile = k >> 9, col = k & 511;
  const int kchunk = lane >> 3;            // dim/32
  const int sslot  = (lane >> 1) & 3;      // (dim&31)/8
  const int rem    = (lane & 1) * 4;       // dim&7
  const size_t off = (size_t)l * (K_CB * D_DIM)
                   + (size_t)(tile * 8 + kchunk) * 16384
                   + (size_t)sslot * 4096 + (size_t)col * 8 + rem;
  *(half4v*)(cb16 + off) = h;
}

// ---------- fused: 128 rows/block resident, 4 layers, GEMM+collect+exact re-rank ----------
__global__ __launch_bounds__(512, 2)
void rq_fused_kernel(const float* __restrict__ x,
                     const float* __restrict__ cb,
                     const float* __restrict__ den,
                     const _Float16* __restrict__ cb16,
                     float* __restrict__ out_ids,
                     float* __restrict__ out_dec,
                     double* __restrict__ dloss) {
  extern __shared__ char sm[];
  _Float16* A16   = (_Float16*)sm;                     // [32 Ksub][128 rows][8h] 64 KB
  _Float16* Bs    = (_Float16*)(sm + 65536);           // 2 x [4 s][512 cols][8h] 32 KB each
  unsigned* cp    = (unsigned*)(sm + 131072);          // [128][CAP] packed (q<<11|idx)
  int*      cn    = (int*)(sm + 131072 + 128*CAP*4);   // [128]
  unsigned* gmax  = (unsigned*)((char*)cn + 512);      // [128] running approx max (fenc)
  unsigned* bestp = (unsigned*)((char*)gmax + 512);    // [128] best packed (fallback)

  const int t = threadIdx.x;
  const int wid = t >> 6, ln = t & 63;
  const int l31 = ln & 31, hl = ln >> 5;
  const int rowg = wid >> 2, colg = wid & 3;           // 2 row-groups x 4 col-groups
  const int urow = t >> 2, qo = (t & 3) * 64;          // r-owner mapping: 4 thr/row
  const int row0 = blockIdx.x * 128;
  const int mrow0 = rowg * 64 + l31, mrow1 = mrow0 + 32;

  // ---- load x quarter into r regs; build A16 (layer-0 input) ----
  float r[64];
  {
    const float4* xg = (const float4*)(x + (size_t)(row0 + urow) * D_DIM + qo);
    #pragma unroll
    for (int i = 0; i < 16; ++i) {
      const float4 a = xg[i];
      r[i*4+0]=a.x; r[i*4+1]=a.y; r[i*4+2]=a.z; r[i*4+3]=a.w;
    }
  }
  #pragma unroll
  for (int j = 0; j < 8; ++j) {
    half8 h;
    #pragma unroll
    for (int e = 0; e < 8; ++e) h[e] = (_Float16)r[j*8+e];
    const int slot = (t & 3) * 8 + j;                  // global K-subslot
    *(half8*)(A16 + slot*1024 + urow*8) = h;
  }
  if (t < 128) { cn[t] = 0; gmax[t] = 0u; bestp[t] = 0u; }
  int id0 = 0, id1 = 0, id2 = 0, id3 = 0;
  double lloss = 0.0;

  #pragma unroll 1
  for (int l = 0; l < L_NUM; ++l) {
    const char* Bimg = (const char*)cb16 + (size_t)l * (K_CB * D_DIM * 2);
    {
      char* dst = (char*)Bs;
      #pragma unroll
      for (int i = 0; i < 4; ++i)
        gl_lds16(Bimg + t*16 + i*8192, dst + t*16 + i*8192);
    }
    __syncthreads();   // A16 ready, resets visible, chunk0 landed

    f32x16 acc[4][2];  // [bi][ai], all indices compile-time (fully unrolled)

    #pragma unroll 1
    for (int g = 0; g < 32; ++g) {
      if ((g & 7) == 0) {
        #pragma unroll
        for (int bi = 0; bi < 4; ++bi)
          #pragma unroll
          for (int ai = 0; ai < 2; ++ai)
            #pragma unroll
            for (int e = 0; e < 16; ++e) acc[bi][ai][e] = 0.f;
      }
      if (g < 31) {                      // prefetch next chunk into other buffer
        char* dst = (char*)Bs + ((g + 1) & 1) * 32768;
        const char* src = Bimg + (size_t)(g + 1) * 32768;
        #pragma unroll
        for (int i = 0; i < 4; ++i)
          gl_lds16(src + t*16 + i*8192, dst + t*16 + i*8192);
      }
      const _Float16* Bb = Bs + (g & 1) * 16384;
      const int cK = g & 7;
      #pragma unroll
      for (int ks2 = 0; ks2 < 2; ++ks2) {
        const int sa = cK*4 + ks2*2 + hl;              // global K-subslot for A
        const int sb = ks2*2 + hl;                     // chunk-local for B
        half8 af[2], bf[4];
        af[0] = *(const half8*)(A16 + sa*1024 + mrow0*8);
        af[1] = *(const half8*)(A16 + sa*1024 + mrow1*8);
        #pragma unroll
        for (int bi = 0; bi < 4; ++bi) {
          const int col = colg*128 + bi*32 + l31;
          bf[bi] = *(const half8*)(Bb + sb*4096 + col*8);
        }
        #pragma unroll
        for (int bi = 0; bi < 4; ++bi) {
          acc[bi][0] = __builtin_amdgcn_mfma_f32_32x32x16_f16(bf[bi], af[0], acc[bi][0], 0, 0, 0);
          acc[bi][1] = __builtin_amdgcn_mfma_f32_32x32x16_f16(bf[bi], af[1], acc[bi][1], 0, 0, 0);
        }
      }
      if ((g & 7) == 7) {                // epilogue per 512-col tile (lane-local rows)
        const int ct = g >> 3;
        #pragma unroll
        for (int ai = 0; ai < 2; ++ai) {
          const int mrow = ai ? mrow1 : mrow0;
          float m = -INFINITY;
          #pragma unroll
          for (int bi = 0; bi < 4; ++bi)
            #pragma unroll
            for (int rg = 0; rg < 16; ++rg) m = fmaxf(m, acc[bi][ai][rg]);
          atomicMax(&gmax[mrow], fenc(m));
          const float thr = fdec(gmax[mrow]) - WACC;   // >= own m - WACC; stale=superset-safe
          #pragma unroll
          for (int bi = 0; bi < 4; ++bi)
            #pragma unroll
            for (int rg = 0; rg < 16; ++rg) {
              const float v = acc[bi][ai][rg];
              if (v >= thr) {
                const unsigned q = (unsigned)((v + 64.f) * 16384.f);   // monotone pack
                const unsigned cidx = (unsigned)(ct*512 + colg*128 + bi*32
                                                 + 4*hl + (rg & 3) + 8*(rg >> 2));
                const unsigned pk = (q << 11) | cidx;
                atomicMax(&bestp[mrow], pk);           // unconditional fallback
                const int slot = atomicAdd(&cn[mrow], 1);
                if (slot < CAP) cp[mrow*CAP + slot] = pk;
              }
            }
        }
      }
      __syncthreads();
    }

    // ---- tail: filter + exact double re-rank (on-the-fly cbn = cb/den) + update ----
    {
      const float thr2 = fdec(gmax[urow]) - WACC2;
      const int m = min(cn[urow], CAP);
      double bsc = (double)INFINITY; int bidx = 0x7fffffff;
      #pragma unroll 1
      for (int j = 0; j <= m; ++j) {                   // j==m: bestp fallback, always ranked
        const unsigned p = (j < m) ? cp[urow*CAP + j] : bestp[urow];
        const float v = (float)(p >> 11) * (1.f/16384.f) - 64.f;
        if (j < m && v < thr2) continue;               // uniform within the 4-thread row group
        const int cidx = (int)(p & 2047u);
        const float dn = den[l*K_CB + cidx];
        const float4* cq = (const float4*)(cb + ((size_t)l*K_CB + cidx)*D_DIM + qo);
        double s = 0.0, n2 = 0.0;
        #pragma unroll
        for (int i = 0; i < 16; ++i) {
          float4 a = cq[i];
          a.x /= dn; a.y /= dn; a.z /= dn; a.w /= dn;  // identical fp32 rounding to prep
          s  = fma((double)r[i*4+0], (double)a.x, s);
          s  = fma((double)r[i*4+1], (double)a.y, s);
          s  = fma((double)r[i*4+2], (double)a.z, s);
          s  = fma((double)r[i*4+3], (double)a.w, s);
          n2 = fma((double)a.x, (double)a.x, n2);
          n2 = fma((double)a.y, (double)a.y, n2);
          n2 = fma((double)a.z, (double)a.z, n2);
          n2 = fma((double)a.w, (double)a.w, n2);
        }
        s  += __shfl_xor(s, 1, 64);  s  += __shfl_xor(s, 2, 64);
        n2 += __shfl_xor(n2, 1, 64); n2 += __shfl_xor(n2, 2, 64);
        const double sc = -2.0 * s + n2;
        if (sc < bsc || (sc == bsc && cidx < bidx)) { bsc = sc; bidx = cidx; }
      }
      bidx &= 2047;                                     // provably valid; belt-and-braces
      if (l == 0) id0 = bidx; else if (l == 1) id1 = bidx;
      else if (l == 2) id2 = bidx; else id3 = bidx;
      if ((t & 3) == 0) out_ids[(size_t)(row0 + urow)*L_NUM + l] = (float)bidx;

      // r -= raw q ; loss += ||r_new||^2
      const float4* qg = (const float4*)(cb + ((size_t)l*K_CB + bidx)*D_DIM + qo);
      #pragma unroll
      for (int i = 0; i < 16; ++i) {
        const float4 q = qg[i];
        r[i*4+0] -= q.x; r[i*4+1] -= q.y; r[i*4+2] -= q.z; r[i*4+3] -= q.w;
        lloss += (double)r[i*4+0]*r[i*4+0] + (double)r[i*4+1]*r[i*4+1]
               + (double)r[i*4+2]*r[i*4+2] + (double)r[i*4+3]*r[i*4+3];
      }
      if (l < 3) {                      // rebuild A16 for next layer
        #pragma unroll
        for (int j = 0; j < 8; ++j) {
          half8 h;
          #pragma unroll
          for (int e = 0; e < 8; ++e) h[e] = (_Float16)r[j*8+e];
          const int slot = (t & 3) * 8 + j;
          *(half8*)(A16 + slot*1024 + urow*8) = h;
        }
      }
    }
    __syncthreads();                    // tail reads of cp/gmax/bestp + A16 writes retired
    if (l < 3 && t < 128) { cn[t] = 0; gmax[t] = 0u; bestp[t] = 0u; }
    // next layer's stage0 + barrier separates these resets from first pushes
  }

  // ---- decoded = ((q0+q1)+q2)+q3 sequential fp32 (reference rounding) ----
  {
    float dec[64];
    #pragma unroll
    for (int l2 = 0; l2 < L_NUM; ++l2) {
      const int idl = (l2 == 0) ? id0 : (l2 == 1) ? id1 : (l2 == 2) ? id2 : id3;
      const float4* qg = (const float4*)(cb + ((size_t)l2*K_CB + idl)*D_DIM + qo);
      #pragma unroll
      for (int i = 0; i < 16; ++i) {
        const float4 q = qg[i];
        if (l2 == 0) { dec[i*4+0]=q.x; dec[i*4+1]=q.y; dec[i*4+2]=q.z; dec[i*4+3]=q.w; }
        else { dec[i*4+0]+=q.x; dec[i*4+1]+=q.y; dec[i*4+2]+=q.z; dec[i*4+3]+=q.w; }
      }
    }
    float4* dg = (float4*)(out_dec + (size_t)(row0 + urow)*D_DIM + qo);
    #pragma unroll
    for (int i = 0; i < 16; ++i)
      dg[i] = make_float4(dec[i*4+0], dec[i*4+1], dec[i*4+2], dec[i*4+3]);
  }

  // ---- loss reduction (lw overlays cp; all cp reads retired before last barrier) ----
  double* lw = (double*)cp;
  #pragma unroll
  for (int m = 1; m < 64; m <<= 1) lloss += __shfl_xor(lloss, m, 64);
  if (ln == 0) lw[wid] = lloss;
  __syncthreads();
  if (t == 0) {
    double s2 = 0.0;
    #pragma unroll
    for (int j = 0; j < 8; ++j) s2 += lw[j];
    atomicAdd(dloss, s2);
  }
}

__global__ void rq_fin_kernel(const double* __restrict__ dls, float* __restrict__ out_loss) {
  // loss = sum_l (1 + BETA) * ||r-q||^2 / n_elem  (codebook and commitment terms equal)
  out_loss[0] = (float)(dls[0] * 1.25 / 8388608.0);
}

extern "C" void kernel_launch(void* const* d_in, const int* in_sizes, int n_in,
                              void* d_out, int out_size, void* d_ws, size_t ws_size,
                              hipStream_t stream) {
  const float* x  = (const float*)d_in[0];
  const float* cb = (const float*)d_in[1];
  float* out      = (float*)d_out;
  float* out_ids  = out;                                   // [N][4] as float
  float* out_dec  = out + (size_t)N_ROWS * L_NUM;          // [N][256]
  float* out_loss = out_dec + (size_t)N_ROWS * D_DIM;

  char* w = (char*)d_ws;
  double* dls = (double*)w;                   w += 256;
  float* den = (float*)w;                     w += (size_t)L_NUM*K_CB*4;
  _Float16* cb16 = (_Float16*)w;              w += (size_t)L_NUM*K_CB*D_DIM*2;

  hipMemsetAsync(dls, 0, sizeof(double), stream);
  prep_all_kernel<<<L_NUM*K_CB, 64, 0, stream>>>(cb, den, cb16);

  const size_t smem = 65536 + 65536 + 128*CAP*4 + 512 + 512 + 512;   // 161280 B
  hipFuncSetAttribute(reinterpret_cast<const void*>(rq_fused_kernel),
                      hipFuncAttributeMaxDynamicSharedMemorySize, (int)smem);
  rq_fused_kernel<<<N_ROWS/128, 512, smem, stream>>>(x, cb, den, cb16,
                                                     out_ids, out_dec, dls);
  rq_fin_kernel<<<1, 1, 0, stream>>>(dls, out_loss);
}

// Round 10
// 351.172 us; speedup vs baseline: 1.2232x; 1.2232x over previous
//
#include <hip/hip_runtime.h>
#include <math.h>

#define L_NUM 4
#define K_CB  2048
#define D_DIM 256
#define N_ROWS 32768
#define CAP 56            // per-row candidate slots (LDS)
#define WACC  0.12f       // collect window (>= 2x worst-case fp16 dot err ~0.032)
#define WACC2 0.125f      // filter window (collect + packing quantization margin)

typedef _Float16 half8 __attribute__((ext_vector_type(8)));
typedef _Float16 half4v __attribute__((ext_vector_type(4)));
typedef float f32x16 __attribute__((ext_vector_type(16)));

__device__ __forceinline__ void gl_lds16(const void* g, void* l) {
  __builtin_amdgcn_global_load_lds(
      (const __attribute__((address_space(1))) void*)g,
      (__attribute__((address_space(3))) void*)l, 16, 0, 0);
}
// monotone float<->uint encoding for atomicMax on floats
__device__ __forceinline__ unsigned fenc(float f) {
  unsigned u = __float_as_uint(f);
  return (u & 0x80000000u) ? ~u : (u | 0x80000000u);
}
__device__ __forceinline__ float fdec(unsigned k) {
  unsigned u = (k & 0x80000000u) ? (k ^ 0x80000000u) : ~k;
  return __uint_as_float(u);
}

// depth-6 pairwise tree max over 64 values (no long dependent chain)
__device__ __forceinline__ float tmax64(const f32x16& a, const f32x16& b,
                                        const f32x16& c, const f32x16& d) {
  float m[16];
  #pragma unroll
  for (int i = 0; i < 16; ++i)
    m[i] = fmaxf(fmaxf(a[i], b[i]), fmaxf(c[i], d[i]));
  #pragma unroll
  for (int s2 = 8; s2 >= 1; s2 >>= 1)
    #pragma unroll
    for (int i = 0; i < s2; ++i) m[i] = fmaxf(m[i], m[i + s2]);
  return m[0];
}

// ---------- prep: cbn fp32 (row-major) + c2d (double ||cbn||^2) + cb16 image ----------
// image chunk c (32 per layer) = cols [(c>>3)*512 .. +512), K-halves [(c&7)*32 .. +32)
// within chunk: [4 subslots][512 cols][8 halves]
__global__ __launch_bounds__(64)
void prep_all_kernel(const float* __restrict__ cb,
                     float* __restrict__ cbn,
                     double* __restrict__ c2d,
                     _Float16* __restrict__ cb16) {
  const int b = blockIdx.x;            // l*2048 + k
  const int k = b & 2047, l = b >> 11;
  const int lane = threadIdx.x;        // 4 dims each
  float4 v = reinterpret_cast<const float4*>(cb + (size_t)b * D_DIM)[lane];
  float s = v.x*v.x + v.y*v.y + v.z*v.z + v.w*v.w;
  #pragma unroll
  for (int m = 1; m < 64; m <<= 1) s += __shfl_xor(s, m, 64);
  const float den = fmaxf(sqrtf(s), 1e-12f);
  v.x /= den; v.y /= den; v.z /= den; v.w /= den;   // true division = reference rounding
  reinterpret_cast<float4*>(cbn + (size_t)b * D_DIM)[lane] = v;
  // exact double ||cbn||^2 of the fp32-rounded values
  double td = (double)v.x*v.x + (double)v.y*v.y + (double)v.z*v.z + (double)v.w*v.w;
  #pragma unroll
  for (int m = 1; m < 64; m <<= 1) td += __shfl_xor(td, m, 64);
  if (lane == 0) c2d[b] = td;
  half4v h;
  h[0] = (_Float16)v.x; h[1] = (_Float16)v.y; h[2] = (_Float16)v.z; h[3] = (_Float16)v.w;
  const int tile = k >> 9, col = k & 511;
  const int kchunk = lane >> 3;            // dim/32
  const int sslot  = (lane >> 1) & 3;      // (dim&31)/8
  const int rem    = (lane & 1) * 4;       // dim&7
  const size_t off = (size_t)l * (K_CB * D_DIM)
                   + (size_t)(tile * 8 + kchunk) * 16384
                   + (size_t)sslot * 4096 + (size_t)col * 8 + rem;
  *(half4v*)(cb16 + off) = h;
}

// ---------- fused: 128 rows/block resident, 4 layers, GEMM+collect+exact re-rank ----------
__global__ __launch_bounds__(512, 2)
void rq_fused_kernel(const float* __restrict__ x,
                     const float* __restrict__ cb,
                     const float* __restrict__ cbn,
                     const double* __restrict__ c2d,
                     const _Float16* __restrict__ cb16,
                     float* __restrict__ out_ids,
                     float* __restrict__ out_dec,
                     double* __restrict__ dloss) {
  extern __shared__ char sm[];
  _Float16* A16   = (_Float16*)sm;                     // [32 Ksub][128 rows][8h] 64 KB
  _Float16* Bs    = (_Float16*)(sm + 65536);           // 2 x [4 s][512 cols][8h] 32 KB each
  unsigned* cp    = (unsigned*)(sm + 131072);          // [128][CAP] packed (q<<11|idx)
  int*      cn    = (int*)(sm + 131072 + 128*CAP*4);   // [128]
  unsigned* gmax  = (unsigned*)((char*)cn + 512);      // [128] running approx max (fenc)
  unsigned* bestp = (unsigned*)((char*)gmax + 512);    // [128] best packed (fallback)

  const int t = threadIdx.x;
  const int wid = t >> 6, ln = t & 63;
  const int l31 = ln & 31, hl = ln >> 5;
  const int rowg = wid >> 2, colg = wid & 3;           // 2 row-groups x 4 col-groups
  const int urow = t >> 2, qo = (t & 3) * 64;          // r-owner mapping: 4 thr/row
  const int row0 = blockIdx.x * 128;
  const int mrow0 = rowg * 64 + l31, mrow1 = mrow0 + 32;

  // ---- load x quarter into r regs; build A16 (layer-0 input) ----
  float r[64];
  {
    const float4* xg = (const float4*)(x + (size_t)(row0 + urow) * D_DIM + qo);
    #pragma unroll
    for (int i = 0; i < 16; ++i) {
      const float4 a = xg[i];
      r[i*4+0]=a.x; r[i*4+1]=a.y; r[i*4+2]=a.z; r[i*4+3]=a.w;
    }
  }
  #pragma unroll
  for (int j = 0; j < 8; ++j) {
    half8 h;
    #pragma unroll
    for (int e = 0; e < 8; ++e) h[e] = (_Float16)r[j*8+e];
    const int slot = (t & 3) * 8 + j;                  // global K-subslot
    *(half8*)(A16 + slot*1024 + urow*8) = h;
  }
  if (t < 128) { cn[t] = 0; gmax[t] = 0u; bestp[t] = 0u; }
  int id0 = 0, id1 = 0, id2 = 0, id3 = 0;
  double lloss = 0.0;

  // stage layer-0 chunk0 (later layers: issued before the previous tail)
  {
    const char* B0 = (const char*)cb16;
    #pragma unroll
    for (int i = 0; i < 4; ++i)
      gl_lds16(B0 + t*16 + i*8192, (char*)Bs + t*16 + i*8192);
  }

  #pragma unroll 1
  for (int l = 0; l < L_NUM; ++l) {
    const char* Bimg = (const char*)cb16 + (size_t)l * (K_CB * D_DIM * 2);
    __syncthreads();   // A16 ready, resets visible, chunk0 landed (vmcnt drained)

    f32x16 acc[4][2];  // [bi][ai], all indices compile-time (fully unrolled)

    #pragma unroll 1
    for (int g = 0; g < 32; ++g) {
      if ((g & 7) == 0) {
        #pragma unroll
        for (int bi = 0; bi < 4; ++bi)
          #pragma unroll
          for (int ai = 0; ai < 2; ++ai)
            #pragma unroll
            for (int e = 0; e < 16; ++e) acc[bi][ai][e] = 0.f;
      }
      if (g < 31) {                      // prefetch next chunk into other buffer
        char* dst = (char*)Bs + ((g + 1) & 1) * 32768;
        const char* src = Bimg + (size_t)(g + 1) * 32768;
        #pragma unroll
        for (int i = 0; i < 4; ++i)
          gl_lds16(src + t*16 + i*8192, dst + t*16 + i*8192);
      }
      const _Float16* Bb = Bs + (g & 1) * 16384;
      const int cK = g & 7;
      #pragma unroll
      for (int ks2 = 0; ks2 < 2; ++ks2) {
        const int sa = cK*4 + ks2*2 + hl;              // global K-subslot for A
        const int sb = ks2*2 + hl;                     // chunk-local for B
        half8 af[2], bf[4];
        af[0] = *(const half8*)(A16 + sa*1024 + mrow0*8);
        af[1] = *(const half8*)(A16 + sa*1024 + mrow1*8);
        #pragma unroll
        for (int bi = 0; bi < 4; ++bi) {
          const int col = colg*128 + bi*32 + l31;
          bf[bi] = *(const half8*)(Bb + sb*4096 + col*8);
        }
        #pragma unroll
        for (int bi = 0; bi < 4; ++bi) {
          acc[bi][0] = __builtin_amdgcn_mfma_f32_32x32x16_f16(bf[bi], af[0], acc[bi][0], 0, 0, 0);
          acc[bi][1] = __builtin_amdgcn_mfma_f32_32x32x16_f16(bf[bi], af[1], acc[bi][1], 0, 0, 0);
        }
      }
      if ((g & 7) == 7) {                // epilogue per 512-col tile (lane-local rows)
        const int ct = g >> 3;
        #pragma unroll
        for (int ai = 0; ai < 2; ++ai) {
          const int mrow = ai ? mrow1 : mrow0;
          const float m = ai ? tmax64(acc[0][1], acc[1][1], acc[2][1], acc[3][1])
                             : tmax64(acc[0][0], acc[1][0], acc[2][0], acc[3][0]);
          atomicMax(&gmax[mrow], fenc(m));
          const float thr = fdec(gmax[mrow]) - WACC;   // >= own m - WACC; stale=superset-safe
          #pragma unroll
          for (int bi = 0; bi < 4; ++bi)
            #pragma unroll
            for (int rg = 0; rg < 16; ++rg) {
              const float v = acc[bi][ai][rg];
              if (v >= thr) {
                const unsigned q = (unsigned)((v + 64.f) * 16384.f);   // monotone pack
                const unsigned cidx = (unsigned)(ct*512 + colg*128 + bi*32
                                                 + 4*hl + (rg & 3) + 8*(rg >> 2));
                const unsigned pk = (q << 11) | cidx;
                atomicMax(&bestp[mrow], pk);           // unconditional fallback
                const int slot = atomicAdd(&cn[mrow], 1);
                if (slot < CAP) cp[mrow*CAP + slot] = pk;
              }
            }
        }
      }
      __syncthreads();
    }

    // overlap: issue NEXT layer's chunk0 now (buf0 idle); drained by layer-top sync
    if (l < 3) {
      const char* Bn = (const char*)cb16 + (size_t)(l + 1) * (K_CB * D_DIM * 2);
      #pragma unroll
      for (int i = 0; i < 4; ++i)
        gl_lds16(Bn + t*16 + i*8192, (char*)Bs + t*16 + i*8192);
    }

    // ---- tail: filter + exact double re-rank (precomputed c2d) + update ----
    {
      const float thr2 = fdec(gmax[urow]) - WACC2;
      const int m = min(cn[urow], CAP);
      double bsc = (double)INFINITY; int bidx = 0x7fffffff;
      #pragma unroll 1
      for (int j = 0; j <= m; ++j) {                   // j==m: bestp fallback, always ranked
        const unsigned p = (j < m) ? cp[urow*CAP + j] : bestp[urow];
        const float v = (float)(p >> 11) * (1.f/16384.f) - 64.f;
        if (j < m && v < thr2) continue;               // uniform within the 4-thread row group
        const int cidx = (int)(p & 2047u);
        const float4* cpn = (const float4*)(cbn + ((size_t)l*K_CB + cidx)*D_DIM + qo);
        double s = 0.0;
        #pragma unroll
        for (int i = 0; i < 16; ++i) {
          const float4 a = cpn[i];
          s = fma((double)r[i*4+0], (double)a.x, s);
          s = fma((double)r[i*4+1], (double)a.y, s);
          s = fma((double)r[i*4+2], (double)a.z, s);
          s = fma((double)r[i*4+3], (double)a.w, s);
        }
        s += __shfl_xor(s, 1, 64);
        s += __shfl_xor(s, 2, 64);
        const double sc = -2.0 * s + c2d[l*K_CB + cidx];
        if (sc < bsc || (sc == bsc && cidx < bidx)) { bsc = sc; bidx = cidx; }
      }
      bidx &= 2047;                                     // provably valid; belt-and-braces
      if (l == 0) id0 = bidx; else if (l == 1) id1 = bidx;
      else if (l == 2) id2 = bidx; else id3 = bidx;
      if ((t & 3) == 0) out_ids[(size_t)(row0 + urow)*L_NUM + l] = (float)bidx;

      // r -= raw q ; loss += ||r_new||^2
      const float4* qg = (const float4*)(cb + ((size_t)l*K_CB + bidx)*D_DIM + qo);
      #pragma unroll
      for (int i = 0; i < 16; ++i) {
        const float4 q = qg[i];
        r[i*4+0] -= q.x; r[i*4+1] -= q.y; r[i*4+2] -= q.z; r[i*4+3] -= q.w;
        lloss += (double)r[i*4+0]*r[i*4+0] + (double)r[i*4+1]*r[i*4+1]
               + (double)r[i*4+2]*r[i*4+2] + (double)r[i*4+3]*r[i*4+3];
      }
      if (l < 3) {                      // rebuild A16 for next layer
        #pragma unroll
        for (int j = 0; j < 8; ++j) {
          half8 h;
          #pragma unroll
          for (int e = 0; e < 8; ++e) h[e] = (_Float16)r[j*8+e];
          const int slot = (t & 3) * 8 + j;
          *(half8*)(A16 + slot*1024 + urow*8) = h;
        }
      }
    }
    __syncthreads();                    // tail reads of cp/gmax/bestp + A16 writes retired
    if (l < 3 && t < 128) { cn[t] = 0; gmax[t] = 0u; bestp[t] = 0u; }
    // layer-top __syncthreads separates these resets from next pushes
  }

  // ---- decoded = ((q0+q1)+q2)+q3 sequential fp32 (reference rounding) ----
  {
    float dec[64];
    #pragma unroll
    for (int l2 = 0; l2 < L_NUM; ++l2) {
      const int idl = (l2 == 0) ? id0 : (l2 == 1) ? id1 : (l2 == 2) ? id2 : id3;
      const float4* qg = (const float4*)(cb + ((size_t)l2*K_CB + idl)*D_DIM + qo);
      #pragma unroll
      for (int i = 0; i < 16; ++i) {
        const float4 q = qg[i];
        if (l2 == 0) { dec[i*4+0]=q.x; dec[i*4+1]=q.y; dec[i*4+2]=q.z; dec[i*4+3]=q.w; }
        else { dec[i*4+0]+=q.x; dec[i*4+1]+=q.y; dec[i*4+2]+=q.z; dec[i*4+3]+=q.w; }
      }
    }
    float4* dg = (float4*)(out_dec + (size_t)(row0 + urow)*D_DIM + qo);
    #pragma unroll
    for (int i = 0; i < 16; ++i)
      dg[i] = make_float4(dec[i*4+0], dec[i*4+1], dec[i*4+2], dec[i*4+3]);
  }

  // ---- loss reduction (lw overlays cp; all cp reads retired before last barrier) ----
  double* lw = (double*)cp;
  #pragma unroll
  for (int m = 1; m < 64; m <<= 1) lloss += __shfl_xor(lloss, m, 64);
  if (ln == 0) lw[wid] = lloss;
  __syncthreads();
  if (t == 0) {
    double s2 = 0.0;
    #pragma unroll
    for (int j = 0; j < 8; ++j) s2 += lw[j];
    atomicAdd(dloss, s2);
  }
}

__global__ void rq_fin_kernel(const double* __restrict__ dls, float* __restrict__ out_loss) {
  // loss = sum_l (1 + BETA) * ||r-q||^2 / n_elem  (codebook and commitment terms equal)
  out_loss[0] = (float)(dls[0] * 1.25 / 8388608.0);
}

extern "C" void kernel_launch(void* const* d_in, const int* in_sizes, int n_in,
                              void* d_out, int out_size, void* d_ws, size_t ws_size,
                              hipStream_t stream) {
  const float* x  = (const float*)d_in[0];
  const float* cb = (const float*)d_in[1];
  float* out      = (float*)d_out;
  float* out_ids  = out;                                   // [N][4] as float
  float* out_dec  = out + (size_t)N_ROWS * L_NUM;          // [N][256]
  float* out_loss = out_dec + (size_t)N_ROWS * D_DIM;

  char* w = (char*)d_ws;
  double* dls = (double*)w;                   w += 256;
  double* c2d = (double*)w;                   w += (size_t)L_NUM*K_CB*8;
  float* cbn = (float*)w;                     w += (size_t)L_NUM*K_CB*D_DIM*4;
  _Float16* cb16 = (_Float16*)w;              w += (size_t)L_NUM*K_CB*D_DIM*2;

  hipMemsetAsync(dls, 0, sizeof(double), stream);
  prep_all_kernel<<<L_NUM*K_CB, 64, 0, stream>>>(cb, cbn, c2d, cb16);

  const size_t smem = 65536 + 65536 + 128*CAP*4 + 512 + 512 + 512;   // 161280 B
  hipFuncSetAttribute(reinterpret_cast<const void*>(rq_fused_kernel),
                      hipFuncAttributeMaxDynamicSharedMemorySize, (int)smem);
  rq_fused_kernel<<<N_ROWS/128, 512, smem, stream>>>(x, cb, cbn, c2d, cb16,
                                                     out_ids, out_dec, dls);
  rq_fin_kernel<<<1, 1, 0, stream>>>(dls, out_loss);
}